// Round 1
// baseline (653.170 us; speedup 1.0000x reference)
//
#include <hip/hip_runtime.h>
#include <hip/hip_bf16.h>
#include <cstddef>
#include <cstdint>

// Problem constants (from reference)
#define NN 50000
#define F_IN 128
#define NH 4
#define NC 64
#define NE 800000
#define NG 128
#define NOUT 8
#define HC 256          // NH*NC
#define EP (NE + NN)    // edges + self loops

// ---------------------------------------------------------------------------
// helpers
// ---------------------------------------------------------------------------
__device__ __forceinline__ float lrelu02(float x) { return x > 0.0f ? x : 0.2f * x; }
__device__ __forceinline__ float elu1(float x)    { return x > 0.0f ? x : expm1f(x); }

// ---------------------------------------------------------------------------
// CSR build: degree histogram -> exclusive scan -> fill (src ids, dst-sorted)
// ---------------------------------------------------------------------------
__global__ void edge_hist(const int* __restrict__ edst, int* __restrict__ deg) {
    int e = blockIdx.x * blockDim.x + threadIdx.x;
    if (e >= EP) return;
    int d = (e < NE) ? edst[e] : (e - NE);
    atomicAdd(&deg[d], 1);
}

__global__ __launch_bounds__(256) void scan_p1(const int* __restrict__ deg,
                                               int* __restrict__ partials) {
    __shared__ int lds[256];
    int b = blockIdx.x, t = threadIdx.x;
    int i0 = b * 1024 + t * 4;
    int s = 0;
#pragma unroll
    for (int j = 0; j < 4; j++) { int i = i0 + j; if (i < NN) s += deg[i]; }
    lds[t] = s;
    __syncthreads();
    for (int o = 128; o; o >>= 1) { if (t < o) lds[t] += lds[t + o]; __syncthreads(); }
    if (t == 0) partials[b] = lds[0];
}

__global__ __launch_bounds__(256) void scan_p3(const int* __restrict__ deg,
                                               const int* __restrict__ partials,
                                               int* __restrict__ offs) {
    __shared__ int lds[256];
    __shared__ int base_s;
    int b = blockIdx.x, t = threadIdx.x;
    if (t == 0) {
        int s = 0;
        for (int i = 0; i < b; i++) s += partials[i];
        base_s = s;
        if (b == 0) offs[0] = 0;
    }
    int i0 = b * 1024 + t * 4;
    int v[4]; int s = 0;
#pragma unroll
    for (int j = 0; j < 4; j++) { int i = i0 + j; v[j] = (i < NN) ? deg[i] : 0; s += v[j]; }
    lds[t] = s;
    __syncthreads();
    for (int o = 1; o < 256; o <<= 1) {
        int x = (t >= o) ? lds[t - o] : 0;
        __syncthreads();
        lds[t] += x;
        __syncthreads();
    }
    int run = base_s + (lds[t] - s);
#pragma unroll
    for (int j = 0; j < 4; j++) { run += v[j]; int i = i0 + j; if (i < NN) offs[i + 1] = run; }
}

__global__ void edge_fill(const int* __restrict__ esrc, const int* __restrict__ edst,
                          const int* __restrict__ offs, int* __restrict__ fill,
                          int* __restrict__ csr) {
    int e = blockIdx.x * blockDim.x + threadIdx.x;
    if (e >= EP) return;
    int s, d;
    if (e < NE) { s = esrc[e]; d = edst[e]; } else { s = d = e - NE; }
    int pos = offs[d] + atomicAdd(&fill[d], 1);
    csr[pos] = s;
}

// ---------------------------------------------------------------------------
// fp32 tiled GEMM: C[M,N] = A[M,K] @ B[K,N], row-major, K%16==0, N%64==0
// BM=BN=64, BK=16, 256 threads, 4x4 per thread
// ---------------------------------------------------------------------------
__global__ __launch_bounds__(256) void gemm_f32(const float* __restrict__ A,
                                                const float* __restrict__ B,
                                                float* __restrict__ C,
                                                int M, int K, int N) {
    __shared__ float As[16][68];
    __shared__ float Bs[16][68];
    int t = threadIdx.x;
    int tx = t & 15, ty = t >> 4;
    int rowBase = blockIdx.x * 64;
    int colBase = blockIdx.y * 64;
    int ar = t >> 2, ak = (t & 3) * 4;   // A: row 0..63, k group
    int bk = t >> 4, bc = (t & 15) * 4;  // B: k 0..15, col group
    float acc[4][4] = {};
    for (int k0 = 0; k0 < K; k0 += 16) {
        int row = rowBase + ar;
        float4 av;
        if (row < M) av = *(const float4*)(A + (size_t)row * K + k0 + ak);
        else { av.x = av.y = av.z = av.w = 0.0f; }
        As[ak + 0][ar] = av.x; As[ak + 1][ar] = av.y;
        As[ak + 2][ar] = av.z; As[ak + 3][ar] = av.w;
        float4 bv = *(const float4*)(B + (size_t)(k0 + bk) * N + colBase + bc);
        *(float4*)&Bs[bk][bc] = bv;
        __syncthreads();
#pragma unroll
        for (int kk = 0; kk < 16; kk++) {
            float4 a = *(const float4*)&As[kk][ty * 4];
            float4 b = *(const float4*)&Bs[kk][tx * 4];
            acc[0][0] += a.x * b.x; acc[0][1] += a.x * b.y; acc[0][2] += a.x * b.z; acc[0][3] += a.x * b.w;
            acc[1][0] += a.y * b.x; acc[1][1] += a.y * b.y; acc[1][2] += a.y * b.z; acc[1][3] += a.y * b.w;
            acc[2][0] += a.z * b.x; acc[2][1] += a.z * b.y; acc[2][2] += a.z * b.z; acc[2][3] += a.z * b.w;
            acc[3][0] += a.w * b.x; acc[3][1] += a.w * b.y; acc[3][2] += a.w * b.z; acc[3][3] += a.w * b.w;
        }
        __syncthreads();
    }
#pragma unroll
    for (int i = 0; i < 4; i++) {
        int row = rowBase + ty * 4 + i;
        if (row < M) {
            float4 v; v.x = acc[i][0]; v.y = acc[i][1]; v.z = acc[i][2]; v.w = acc[i][3];
            *(float4*)(C + (size_t)row * N + colBase + tx * 4) = v;
        }
    }
}

// ---------------------------------------------------------------------------
// per-node attention logits: asrc[n,h] = sum_c h[n,h,c]*a_s[h,c] (same for dst)
// one wave per node, lanes = channels
// ---------------------------------------------------------------------------
__global__ __launch_bounds__(256) void gat_alpha(const float* __restrict__ h,
                                                 const float* __restrict__ a_s,
                                                 const float* __restrict__ a_d,
                                                 float* __restrict__ asrc,
                                                 float* __restrict__ adst) {
    int wave = threadIdx.x >> 6, lane = threadIdx.x & 63;
    int node = blockIdx.x * 4 + wave;
    if (node >= NN) return;
    const float* hp = h + (size_t)node * HC + lane;
    float rs[NH], rd[NH];
#pragma unroll
    for (int hh = 0; hh < NH; hh++) {
        float v = hp[hh * 64];
        float ps = v * a_s[hh * 64 + lane];
        float pd = v * a_d[hh * 64 + lane];
        for (int o = 32; o; o >>= 1) { ps += __shfl_xor(ps, o); pd += __shfl_xor(pd, o); }
        rs[hh] = ps; rd[hh] = pd;
    }
    if (lane == 0) {
        float4 s4; s4.x = rs[0]; s4.y = rs[1]; s4.z = rs[2]; s4.w = rs[3];
        float4 d4; d4.x = rd[0]; d4.y = rd[1]; d4.z = rd[2]; d4.w = rd[3];
        *(float4*)(asrc + node * 4) = s4;
        *(float4*)(adst + node * 4) = d4;
    }
}

// ---------------------------------------------------------------------------
// GAT aggregation: one wave per destination node. lanes = 64 channels.
// Pass 1: online softmax over incident edges (per-edge logits kept 1/lane in
// registers for deg<=64 — true for this input, fallback recompute otherwise).
// Pass 2: weighted gather-accumulate of h[src] rows (coalesced 256B/head).
// CONCAT=1: out[n,256] = elu(acc + b); CONCAT=0: out[n,64] = mean_h(acc) + b.
// ---------------------------------------------------------------------------
template <int CONCAT>
__global__ __launch_bounds__(256) void gat_agg(const float* __restrict__ h,
                                               const float* __restrict__ asrc,
                                               const float* __restrict__ adst,
                                               const int* __restrict__ offs,
                                               const int* __restrict__ csr,
                                               const float* __restrict__ bias,
                                               float* __restrict__ out) {
    int wave = threadIdx.x >> 6, lane = threadIdx.x & 63;
    int node = blockIdx.x * 4 + wave;
    if (node >= NN) return;
    int start = offs[node];
    int deg = offs[node + 1] - start;
    float4 ad = *(const float4*)(adst + node * 4);

    // pass 1: per-lane online softmax state (4 heads)
    float m0 = -1e30f, m1 = -1e30f, m2 = -1e30f, m3 = -1e30f;
    float s0 = 0.f, s1 = 0.f, s2 = 0.f, s3 = 0.f;
    float e0 = 0.f, e1 = 0.f, e2 = 0.f, e3 = 0.f;
    int msrc = 0;
    for (int j = lane; j < deg; j += 64) {
        int sidx = csr[start + j];
        float4 as = *(const float4*)(asrc + sidx * 4);
        float t0 = lrelu02(as.x + ad.x);
        float t1 = lrelu02(as.y + ad.y);
        float t2 = lrelu02(as.z + ad.z);
        float t3 = lrelu02(as.w + ad.w);
        if (j == lane) { e0 = t0; e1 = t1; e2 = t2; e3 = t3; msrc = sidx; }
        float nm;
        nm = fmaxf(m0, t0); s0 = s0 * __expf(m0 - nm) + __expf(t0 - nm); m0 = nm;
        nm = fmaxf(m1, t1); s1 = s1 * __expf(m1 - nm) + __expf(t1 - nm); m1 = nm;
        nm = fmaxf(m2, t2); s2 = s2 * __expf(m2 - nm) + __expf(t2 - nm); m2 = nm;
        nm = fmaxf(m3, t3); s3 = s3 * __expf(m3 - nm) + __expf(t3 - nm); m3 = nm;
    }
    // combine lanes
    for (int o = 32; o; o >>= 1) {
        float om, os, nm;
        om = __shfl_xor(m0, o); os = __shfl_xor(s0, o);
        nm = fmaxf(m0, om); s0 = s0 * __expf(m0 - nm) + os * __expf(om - nm); m0 = nm;
        om = __shfl_xor(m1, o); os = __shfl_xor(s1, o);
        nm = fmaxf(m1, om); s1 = s1 * __expf(m1 - nm) + os * __expf(om - nm); m1 = nm;
        om = __shfl_xor(m2, o); os = __shfl_xor(s2, o);
        nm = fmaxf(m2, om); s2 = s2 * __expf(m2 - nm) + os * __expf(om - nm); m2 = nm;
        om = __shfl_xor(m3, o); os = __shfl_xor(s3, o);
        nm = fmaxf(m3, om); s3 = s3 * __expf(m3 - nm) + os * __expf(om - nm); m3 = nm;
    }
    float inv0 = 1.0f / (s0 + 1e-16f);
    float inv1 = 1.0f / (s1 + 1e-16f);
    float inv2 = 1.0f / (s2 + 1e-16f);
    float inv3 = 1.0f / (s3 + 1e-16f);

    // pass 2: weighted accumulate, lanes = channels
    float a0 = 0.f, a1 = 0.f, a2 = 0.f, a3 = 0.f;
    const float* hb = h + lane;
    int jmax = deg < 64 ? deg : 64;
    for (int j = 0; j < jmax; j++) {
        int sidx = __shfl(msrc, j);
        float w0 = __expf(__shfl(e0, j) - m0) * inv0;
        float w1 = __expf(__shfl(e1, j) - m1) * inv1;
        float w2 = __expf(__shfl(e2, j) - m2) * inv2;
        float w3 = __expf(__shfl(e3, j) - m3) * inv3;
        const float* hp = hb + (size_t)sidx * HC;
        a0 += w0 * hp[0];
        a1 += w1 * hp[64];
        a2 += w2 * hp[128];
        a3 += w3 * hp[192];
    }
    for (int j = 64; j < deg; j++) {  // correctness fallback (deg>64); not hit here
        int sidx = csr[start + j];
        float4 as = *(const float4*)(asrc + sidx * 4);
        float w0 = __expf(lrelu02(as.x + ad.x) - m0) * inv0;
        float w1 = __expf(lrelu02(as.y + ad.y) - m1) * inv1;
        float w2 = __expf(lrelu02(as.z + ad.z) - m2) * inv2;
        float w3 = __expf(lrelu02(as.w + ad.w) - m3) * inv3;
        const float* hp = hb + (size_t)sidx * HC;
        a0 += w0 * hp[0];
        a1 += w1 * hp[64];
        a2 += w2 * hp[128];
        a3 += w3 * hp[192];
    }

    if (CONCAT) {
        size_t base = (size_t)node * HC;
        out[base + lane]       = elu1(a0 + bias[lane]);
        out[base + 64 + lane]  = elu1(a1 + bias[64 + lane]);
        out[base + 128 + lane] = elu1(a2 + bias[128 + lane]);
        out[base + 192 + lane] = elu1(a3 + bias[192 + lane]);
    } else {
        out[(size_t)node * NC + lane] = 0.25f * (a0 + a1 + a2 + a3) + bias[lane];
    }
}

// ---------------------------------------------------------------------------
// global mean pool (batch sorted): run-accumulate 16 nodes/wave, then atomics
// ---------------------------------------------------------------------------
__global__ __launch_bounds__(256) void pool_kernel(const float* __restrict__ out2,
                                                   const int* __restrict__ batch,
                                                   float* __restrict__ pool,
                                                   float* __restrict__ cnt) {
    int gw = (blockIdx.x * blockDim.x + threadIdx.x) >> 6;
    int lane = threadIdx.x & 63;
    int start = gw * 16;
    if (start >= NN) return;
    int end = start + 16 < NN ? start + 16 : NN;
    int curg = batch[start];
    float acc = 0.f; int run = 0;
    for (int node = start; node < end; node++) {
        int g = batch[node];
        if (g != curg) {
            atomicAdd(&pool[curg * 64 + lane], acc);
            if (lane == 0) atomicAdd(&cnt[curg], (float)run);
            curg = g; acc = 0.f; run = 0;
        }
        acc += out2[(size_t)node * NC + lane];
        run++;
    }
    atomicAdd(&pool[curg * 64 + lane], acc);
    if (lane == 0) atomicAdd(&cnt[curg], (float)run);
}

__global__ void fc_kernel(const float* __restrict__ pool, const float* __restrict__ cnt,
                          const float* __restrict__ fc_w, const float* __restrict__ fc_b,
                          float* __restrict__ out) {
    int idx = blockIdx.x * blockDim.x + threadIdx.x;
    if (idx >= NG * NOUT) return;
    int g = idx >> 3, o = idx & 7;
    float inv = 1.0f / fmaxf(cnt[g], 1.0f);
    float s = 0.f;
#pragma unroll
    for (int c = 0; c < 64; c++) s += pool[g * 64 + c] * fc_w[c * 8 + o];
    out[idx] = s * inv + fc_b[o];
}

// ---------------------------------------------------------------------------
extern "C" void kernel_launch(void* const* d_in, const int* in_sizes, int n_in,
                              void* d_out, int out_size, void* d_ws, size_t ws_size,
                              hipStream_t stream) {
    const float* x    = (const float*)d_in[0];
    const int*   ei   = (const int*)d_in[1];   // [2, E]
    const int*   batch= (const int*)d_in[2];
    const float* W1   = (const float*)d_in[3];
    const float* a1s  = (const float*)d_in[4];
    const float* a1d  = (const float*)d_in[5];
    const float* b1   = (const float*)d_in[6];
    const float* W2   = (const float*)d_in[7];
    const float* a2s  = (const float*)d_in[8];
    const float* a2d  = (const float*)d_in[9];
    const float* b2   = (const float*)d_in[10];
    const float* fc_w = (const float*)d_in[11];
    const float* fc_b = (const float*)d_in[12];
    float* out = (float*)d_out;

    // workspace layout (all 256B aligned)
    char* p = (char*)d_ws;
    auto alloc = [&](size_t bytes) -> char* {
        char* r = p; p += (bytes + 255) & ~(size_t)255; return r;
    };
    int*   deg     = (int*)alloc((size_t)NN * 4);
    int*   fill    = (int*)alloc((size_t)NN * 4);
    float* pool    = (float*)alloc((size_t)NG * 64 * 4);
    float* cnt     = (float*)alloc((size_t)NG * 4);
    size_t zero_bytes = (size_t)(p - (char*)d_ws);
    int*   offs    = (int*)alloc((size_t)(NN + 1) * 4);
    int*   partials= (int*)alloc(64 * 4);
    int*   csr     = (int*)alloc((size_t)EP * 4);
    float* asrc    = (float*)alloc((size_t)NN * 4 * 4);
    float* adst    = (float*)alloc((size_t)NN * 4 * 4);
    float* h       = (float*)alloc((size_t)NN * HC * 4);   // h1, reused as h2
    float* act     = (float*)alloc((size_t)NN * HC * 4);   // elu(gat1 out)
    float* out2    = (float*)alloc((size_t)NN * NC * 4);

    hipMemsetAsync(d_ws, 0, zero_bytes, stream);

    int eb = (EP + 255) / 256;
    edge_hist<<<eb, 256, 0, stream>>>(ei + NE, deg);
    scan_p1<<<49, 256, 0, stream>>>(deg, partials);
    scan_p3<<<49, 256, 0, stream>>>(deg, partials, offs);
    edge_fill<<<eb, 256, 0, stream>>>(ei, ei + NE, offs, fill, csr);

    dim3 gg((NN + 63) / 64, HC / 64);
    int nb4 = (NN + 3) / 4;

    // layer 1
    gemm_f32<<<gg, 256, 0, stream>>>(x, W1, h, NN, F_IN, HC);
    gat_alpha<<<nb4, 256, 0, stream>>>(h, a1s, a1d, asrc, adst);
    gat_agg<1><<<nb4, 256, 0, stream>>>(h, asrc, adst, offs, csr, b1, act);
    // layer 2
    gemm_f32<<<gg, 256, 0, stream>>>(act, W2, h, NN, HC, HC);
    gat_alpha<<<nb4, 256, 0, stream>>>(h, a2s, a2d, asrc, adst);
    gat_agg<0><<<nb4, 256, 0, stream>>>(h, asrc, adst, offs, csr, b2, out2);
    // readout
    pool_kernel<<<((NN + 15) / 16 + 3) / 4, 256, 0, stream>>>(out2, batch, pool, cnt);
    fc_kernel<<<(NG * NOUT + 255) / 256, 256, 0, stream>>>(pool, cnt, fc_w, fc_b, out);
}

// Round 2
// 563.509 us; speedup vs baseline: 1.1591x; 1.1591x over previous
//
#include <hip/hip_runtime.h>
#include <hip/hip_bf16.h>
#include <cstddef>
#include <cstdint>

// Problem constants (from reference)
#define NN 50000
#define MPAD 50048      // 391 tiles * 128
#define F_IN 128
#define NH 4
#define NC 64
#define NE 800000
#define NG 128
#define NOUT 8
#define HC 256          // NH*NC
#define EP (NE + NN)    // edges + self loops

typedef unsigned short ushort_t;
typedef __attribute__((ext_vector_type(8))) short bf16x8;
typedef __attribute__((ext_vector_type(4))) float f32x4;

// ---------------------------------------------------------------------------
// helpers
// ---------------------------------------------------------------------------
__device__ __forceinline__ float lrelu02(float x) { return x > 0.0f ? x : 0.2f * x; }
__device__ __forceinline__ float elu1(float x)    { return x > 0.0f ? x : expm1f(x); }

__device__ __forceinline__ ushort_t f2bf(float f) {
    uint32_t u = __float_as_uint(f);
    uint32_t r = u + 0x7fffu + ((u >> 16) & 1u);
    return (ushort_t)(r >> 16);
}
__device__ __forceinline__ float bf2f(ushort_t h) {
    return __uint_as_float(((uint32_t)h) << 16);
}

// async global -> LDS, 16B per lane; lds dest = wave-uniform base + lane*16
__device__ __forceinline__ void gld16(const void* g, void* l) {
    __builtin_amdgcn_global_load_lds(
        (const __attribute__((address_space(1))) unsigned int*)g,
        (__attribute__((address_space(3))) unsigned int*)l, 16, 0, 0);
}

// ---------------------------------------------------------------------------
// CSR build: degree histogram -> exclusive scan -> fill (src ids, dst-sorted)
// ---------------------------------------------------------------------------
__global__ void edge_hist(const int* __restrict__ edst, int* __restrict__ deg) {
    int e = blockIdx.x * blockDim.x + threadIdx.x;
    if (e >= EP) return;
    int d = (e < NE) ? edst[e] : (e - NE);
    atomicAdd(&deg[d], 1);
}

__global__ __launch_bounds__(256) void scan_p1(const int* __restrict__ deg,
                                               int* __restrict__ partials) {
    __shared__ int lds[256];
    int b = blockIdx.x, t = threadIdx.x;
    int i0 = b * 1024 + t * 4;
    int s = 0;
#pragma unroll
    for (int j = 0; j < 4; j++) { int i = i0 + j; if (i < NN) s += deg[i]; }
    lds[t] = s;
    __syncthreads();
    for (int o = 128; o; o >>= 1) { if (t < o) lds[t] += lds[t + o]; __syncthreads(); }
    if (t == 0) partials[b] = lds[0];
}

__global__ __launch_bounds__(256) void scan_p3(const int* __restrict__ deg,
                                               const int* __restrict__ partials,
                                               int* __restrict__ offs) {
    __shared__ int lds[256];
    __shared__ int base_s;
    int b = blockIdx.x, t = threadIdx.x;
    if (t == 0) {
        int s = 0;
        for (int i = 0; i < b; i++) s += partials[i];
        base_s = s;
        if (b == 0) offs[0] = 0;
    }
    int i0 = b * 1024 + t * 4;
    int v[4]; int s = 0;
#pragma unroll
    for (int j = 0; j < 4; j++) { int i = i0 + j; v[j] = (i < NN) ? deg[i] : 0; s += v[j]; }
    lds[t] = s;
    __syncthreads();
    for (int o = 1; o < 256; o <<= 1) {
        int x = (t >= o) ? lds[t - o] : 0;
        __syncthreads();
        lds[t] += x;
        __syncthreads();
    }
    int run = base_s + (lds[t] - s);
#pragma unroll
    for (int j = 0; j < 4; j++) { run += v[j]; int i = i0 + j; if (i < NN) offs[i + 1] = run; }
}

__global__ void edge_fill(const int* __restrict__ esrc, const int* __restrict__ edst,
                          const int* __restrict__ offs, int* __restrict__ fill,
                          int* __restrict__ csr) {
    int e = blockIdx.x * blockDim.x + threadIdx.x;
    if (e >= EP) return;
    int s, d;
    if (e < NE) { s = esrc[e]; d = edst[e]; } else { s = d = e - NE; }
    int pos = offs[d] + atomicAdd(&fill[d], 1);
    csr[pos] = s;
}

// ---------------------------------------------------------------------------
// fp32 -> (bf16 hi, bf16 lo) split, vectorized
// ---------------------------------------------------------------------------
__global__ void split_f32(const float* __restrict__ in, ushort_t* __restrict__ hi,
                          ushort_t* __restrict__ lo, int n4) {
    int i = blockIdx.x * blockDim.x + threadIdx.x;
    if (i >= n4) return;
    float4 v = ((const float4*)in)[i];
    ushort4 h, l;
    h.x = f2bf(v.x); l.x = f2bf(v.x - bf2f(h.x));
    h.y = f2bf(v.y); l.y = f2bf(v.y - bf2f(h.y));
    h.z = f2bf(v.z); l.z = f2bf(v.z - bf2f(h.z));
    h.w = f2bf(v.w); l.w = f2bf(v.w - bf2f(h.w));
    ((ushort4*)hi)[i] = h;
    ((ushort4*)lo)[i] = l;
}

// W [K,N] fp32 -> WT hi/lo [N,K] bf16 (transposed planes for MFMA B-operand)
__global__ void split_wT(const float* __restrict__ W, ushort_t* __restrict__ hiT,
                         ushort_t* __restrict__ loT, int K, int N) {
    int idx = blockIdx.x * blockDim.x + threadIdx.x;
    if (idx >= K * N) return;
    int k = idx / N, n = idx % N;
    float v = W[idx];
    ushort_t h = f2bf(v);
    hiT[n * K + k] = h;
    loT[n * K + k] = f2bf(v - bf2f(h));
}

// ---------------------------------------------------------------------------
// split-bf16 MFMA GEMM: C[M,N] fp32 = (Ahi+Alo) @ (Bhi+Blo), dropping lo*lo.
// A planes: [MPAD,K] bf16 row-major. B planes: BT [N,K] bf16 (row = n).
// Block: 256 thr (4 waves, 2x2), tile 128x128, BK=32, mfma_f32_16x16x32_bf16.
// A-frag: A[m=lane&15][k=quad*8+j]; B-frag: BT[n=lane&15][k=quad*8+j];
// C/D: col=lane&15, row=quad*4+reg (m89/m91-verified).
// ---------------------------------------------------------------------------
__global__ __launch_bounds__(256, 2) void gemm_bf3(
        const ushort_t* __restrict__ Ahi, const ushort_t* __restrict__ Alo,
        const ushort_t* __restrict__ BThi, const ushort_t* __restrict__ BTlo,
        float* __restrict__ C, int M, int K, int N) {
    __shared__ alignas(16) ushort_t lAhi[128 * 32];
    __shared__ alignas(16) ushort_t lAlo[128 * 32];
    __shared__ alignas(16) ushort_t lBhi[128 * 32];
    __shared__ alignas(16) ushort_t lBlo[128 * 32];

    int t = threadIdx.x;
    int wave = t >> 6, lane = t & 63;
    int wm = wave >> 1, wn = wave & 1;
    int quad = lane >> 4, l15 = lane & 15;
    int tileM = blockIdx.x * 128;
    int tileN = blockIdx.y * 128;

    f32x4 acc[4][4];
#pragma unroll
    for (int f = 0; f < 4; f++)
#pragma unroll
        for (int g = 0; g < 4; g++) acc[f][g] = (f32x4){0.f, 0.f, 0.f, 0.f};

    // staging geometry: chunk c covers rows c*16..c*16+15 (64B/row per plane);
    // lane l -> row c*16 + (l>>2), byte offset (l&3)*16 == lane*16 from base.
    int c0 = wave * 2;

    for (int k0 = 0; k0 < K; k0 += 32) {
        __syncthreads();   // previous chunk's compute done before overwrite
#pragma unroll
        for (int i = 0; i < 2; i++) {
            int c = c0 + i;
            int row = c * 16 + (lane >> 2);
            int kk = k0 + (lane & 3) * 8;
            size_t aoff = (size_t)(tileM + row) * K + kk;
            size_t boff = (size_t)(tileN + row) * K + kk;
            gld16(Ahi + aoff, &lAhi[c * 512]);
            gld16(Alo + aoff, &lAlo[c * 512]);
            gld16(BThi + boff, &lBhi[c * 512]);
            gld16(BTlo + boff, &lBlo[c * 512]);
        }
        __syncthreads();   // drains vmcnt (global_load_lds) before LDS reads

        bf16x8 ah[4], al[4], bh[4], bl[4];
#pragma unroll
        for (int f = 0; f < 4; f++) {
            int m = wm * 64 + f * 16 + l15;
            ah[f] = *(const bf16x8*)&lAhi[m * 32 + quad * 8];
            al[f] = *(const bf16x8*)&lAlo[m * 32 + quad * 8];
        }
#pragma unroll
        for (int g = 0; g < 4; g++) {
            int n = wn * 64 + g * 16 + l15;
            bh[g] = *(const bf16x8*)&lBhi[n * 32 + quad * 8];
            bl[g] = *(const bf16x8*)&lBlo[n * 32 + quad * 8];
        }
#pragma unroll
        for (int f = 0; f < 4; f++)
#pragma unroll
            for (int g = 0; g < 4; g++) {
                acc[f][g] = __builtin_amdgcn_mfma_f32_16x16x32_bf16(ah[f], bh[g], acc[f][g], 0, 0, 0);
                acc[f][g] = __builtin_amdgcn_mfma_f32_16x16x32_bf16(ah[f], bl[g], acc[f][g], 0, 0, 0);
                acc[f][g] = __builtin_amdgcn_mfma_f32_16x16x32_bf16(al[f], bh[g], acc[f][g], 0, 0, 0);
            }
    }

#pragma unroll
    for (int f = 0; f < 4; f++) {
#pragma unroll
        for (int g = 0; g < 4; g++) {
            int col = tileN + wn * 64 + g * 16 + l15;
#pragma unroll
            for (int r = 0; r < 4; r++) {
                int row = tileM + wm * 64 + f * 16 + quad * 4 + r;
                if (row < M) C[(size_t)row * N + col] = acc[f][g][r];
            }
        }
    }
}

// ---------------------------------------------------------------------------
// per-node attention logits: asrc[n,h] = sum_c h[n,h,c]*a_s[h,c] (same for dst)
// ---------------------------------------------------------------------------
__global__ __launch_bounds__(256) void gat_alpha(const float* __restrict__ h,
                                                 const float* __restrict__ a_s,
                                                 const float* __restrict__ a_d,
                                                 float* __restrict__ asrc,
                                                 float* __restrict__ adst) {
    int wave = threadIdx.x >> 6, lane = threadIdx.x & 63;
    int node = blockIdx.x * 4 + wave;
    if (node >= NN) return;
    const float* hp = h + (size_t)node * HC + lane;
    float rs[NH], rd[NH];
#pragma unroll
    for (int hh = 0; hh < NH; hh++) {
        float v = hp[hh * 64];
        float ps = v * a_s[hh * 64 + lane];
        float pd = v * a_d[hh * 64 + lane];
        for (int o = 32; o; o >>= 1) { ps += __shfl_xor(ps, o); pd += __shfl_xor(pd, o); }
        rs[hh] = ps; rd[hh] = pd;
    }
    if (lane == 0) {
        float4 s4; s4.x = rs[0]; s4.y = rs[1]; s4.z = rs[2]; s4.w = rs[3];
        float4 d4; d4.x = rd[0]; d4.y = rd[1]; d4.z = rd[2]; d4.w = rd[3];
        *(float4*)(asrc + node * 4) = s4;
        *(float4*)(adst + node * 4) = d4;
    }
}

// ---------------------------------------------------------------------------
// GAT aggregation: one wave per destination node, lanes = 64 channels.
// Pass 1: online softmax over edges (logits 1/lane for deg<=64).
// Weights precomputed per-lane once (no per-edge expf in pass 2).
// CONCAT=1: writes bf16 hi/lo split of elu(acc+b) (feeds gemm_bf3 layer 2).
// CONCAT=0: writes fp32 mean over heads + bias.
// ---------------------------------------------------------------------------
template <int CONCAT>
__global__ __launch_bounds__(256) void gat_agg(const float* __restrict__ h,
                                               const float* __restrict__ asrc,
                                               const float* __restrict__ adst,
                                               const int* __restrict__ offs,
                                               const int* __restrict__ csr,
                                               const float* __restrict__ bias,
                                               ushort_t* __restrict__ oh,
                                               ushort_t* __restrict__ ol,
                                               float* __restrict__ of) {
    int wave = threadIdx.x >> 6, lane = threadIdx.x & 63;
    int node = blockIdx.x * 4 + wave;
    if (node >= NN) return;
    int start = offs[node];
    int deg = offs[node + 1] - start;
    float4 ad = *(const float4*)(adst + node * 4);

    float m0 = -1e30f, m1 = -1e30f, m2 = -1e30f, m3 = -1e30f;
    float s0 = 0.f, s1 = 0.f, s2 = 0.f, s3 = 0.f;
    float e0 = 0.f, e1 = 0.f, e2 = 0.f, e3 = 0.f;
    int msrc = 0;
    for (int j = lane; j < deg; j += 64) {
        int sidx = csr[start + j];
        float4 as = *(const float4*)(asrc + sidx * 4);
        float t0 = lrelu02(as.x + ad.x);
        float t1 = lrelu02(as.y + ad.y);
        float t2 = lrelu02(as.z + ad.z);
        float t3 = lrelu02(as.w + ad.w);
        if (j == lane) { e0 = t0; e1 = t1; e2 = t2; e3 = t3; msrc = sidx; }
        float nm;
        nm = fmaxf(m0, t0); s0 = s0 * __expf(m0 - nm) + __expf(t0 - nm); m0 = nm;
        nm = fmaxf(m1, t1); s1 = s1 * __expf(m1 - nm) + __expf(t1 - nm); m1 = nm;
        nm = fmaxf(m2, t2); s2 = s2 * __expf(m2 - nm) + __expf(t2 - nm); m2 = nm;
        nm = fmaxf(m3, t3); s3 = s3 * __expf(m3 - nm) + __expf(t3 - nm); m3 = nm;
    }
    for (int o = 32; o; o >>= 1) {
        float om, os, nm;
        om = __shfl_xor(m0, o); os = __shfl_xor(s0, o);
        nm = fmaxf(m0, om); s0 = s0 * __expf(m0 - nm) + os * __expf(om - nm); m0 = nm;
        om = __shfl_xor(m1, o); os = __shfl_xor(s1, o);
        nm = fmaxf(m1, om); s1 = s1 * __expf(m1 - nm) + os * __expf(om - nm); m1 = nm;
        om = __shfl_xor(m2, o); os = __shfl_xor(s2, o);
        nm = fmaxf(m2, om); s2 = s2 * __expf(m2 - nm) + os * __expf(om - nm); m2 = nm;
        om = __shfl_xor(m3, o); os = __shfl_xor(s3, o);
        nm = fmaxf(m3, om); s3 = s3 * __expf(m3 - nm) + os * __expf(om - nm); m3 = nm;
    }
    float inv0 = 1.0f / (s0 + 1e-16f);
    float inv1 = 1.0f / (s1 + 1e-16f);
    float inv2 = 1.0f / (s2 + 1e-16f);
    float inv3 = 1.0f / (s3 + 1e-16f);

    // per-lane normalized weight, computed ONCE (was 64x-redundant expf/edge)
    float w0 = __expf(e0 - m0) * inv0;
    float w1 = __expf(e1 - m1) * inv1;
    float w2 = __expf(e2 - m2) * inv2;
    float w3 = __expf(e3 - m3) * inv3;

    float a0 = 0.f, a1 = 0.f, a2 = 0.f, a3 = 0.f;
    const float* hb = h + lane;
    int jmax = deg < 64 ? deg : 64;
#pragma unroll 2
    for (int j = 0; j < jmax; j++) {
        int sidx = __shfl(msrc, j);
        float u0 = __shfl(w0, j);
        float u1 = __shfl(w1, j);
        float u2 = __shfl(w2, j);
        float u3 = __shfl(w3, j);
        const float* hp = hb + (size_t)sidx * HC;
        a0 += u0 * hp[0];
        a1 += u1 * hp[64];
        a2 += u2 * hp[128];
        a3 += u3 * hp[192];
    }
    for (int j = 64; j < deg; j++) {  // correctness fallback (deg>64); not hit here
        int sidx = csr[start + j];
        float4 as = *(const float4*)(asrc + sidx * 4);
        float u0 = __expf(lrelu02(as.x + ad.x) - m0) * inv0;
        float u1 = __expf(lrelu02(as.y + ad.y) - m1) * inv1;
        float u2 = __expf(lrelu02(as.z + ad.z) - m2) * inv2;
        float u3 = __expf(lrelu02(as.w + ad.w) - m3) * inv3;
        const float* hp = hb + (size_t)sidx * HC;
        a0 += u0 * hp[0];
        a1 += u1 * hp[64];
        a2 += u2 * hp[128];
        a3 += u3 * hp[192];
    }

    if (CONCAT) {
        size_t base = (size_t)node * HC;
        float v0 = elu1(a0 + bias[lane]);
        float v1 = elu1(a1 + bias[64 + lane]);
        float v2 = elu1(a2 + bias[128 + lane]);
        float v3 = elu1(a3 + bias[192 + lane]);
        ushort_t h0 = f2bf(v0), h1 = f2bf(v1), h2 = f2bf(v2), h3 = f2bf(v3);
        oh[base + lane]       = h0; ol[base + lane]       = f2bf(v0 - bf2f(h0));
        oh[base + 64 + lane]  = h1; ol[base + 64 + lane]  = f2bf(v1 - bf2f(h1));
        oh[base + 128 + lane] = h2; ol[base + 128 + lane] = f2bf(v2 - bf2f(h2));
        oh[base + 192 + lane] = h3; ol[base + 192 + lane] = f2bf(v3 - bf2f(h3));
    } else {
        of[(size_t)node * NC + lane] = 0.25f * (a0 + a1 + a2 + a3) + bias[lane];
    }
}

// ---------------------------------------------------------------------------
// global mean pool (batch sorted) + FC
// ---------------------------------------------------------------------------
__global__ __launch_bounds__(256) void pool_kernel(const float* __restrict__ out2,
                                                   const int* __restrict__ batch,
                                                   float* __restrict__ pool,
                                                   float* __restrict__ cnt) {
    int gw = (blockIdx.x * blockDim.x + threadIdx.x) >> 6;
    int lane = threadIdx.x & 63;
    int start = gw * 16;
    if (start >= NN) return;
    int end = start + 16 < NN ? start + 16 : NN;
    int curg = batch[start];
    float acc = 0.f; int run = 0;
    for (int node = start; node < end; node++) {
        int g = batch[node];
        if (g != curg) {
            atomicAdd(&pool[curg * 64 + lane], acc);
            if (lane == 0) atomicAdd(&cnt[curg], (float)run);
            curg = g; acc = 0.f; run = 0;
        }
        acc += out2[(size_t)node * NC + lane];
        run++;
    }
    atomicAdd(&pool[curg * 64 + lane], acc);
    if (lane == 0) atomicAdd(&cnt[curg], (float)run);
}

__global__ void fc_kernel(const float* __restrict__ pool, const float* __restrict__ cnt,
                          const float* __restrict__ fc_w, const float* __restrict__ fc_b,
                          float* __restrict__ out) {
    int idx = blockIdx.x * blockDim.x + threadIdx.x;
    if (idx >= NG * NOUT) return;
    int g = idx >> 3, o = idx & 7;
    float inv = 1.0f / fmaxf(cnt[g], 1.0f);
    float s = 0.f;
#pragma unroll
    for (int c = 0; c < 64; c++) s += pool[g * 64 + c] * fc_w[c * 8 + o];
    out[idx] = s * inv + fc_b[o];
}

// ---------------------------------------------------------------------------
extern "C" void kernel_launch(void* const* d_in, const int* in_sizes, int n_in,
                              void* d_out, int out_size, void* d_ws, size_t ws_size,
                              hipStream_t stream) {
    const float* x    = (const float*)d_in[0];
    const int*   ei   = (const int*)d_in[1];   // [2, E]
    const int*   batch= (const int*)d_in[2];
    const float* W1   = (const float*)d_in[3];
    const float* a1s  = (const float*)d_in[4];
    const float* a1d  = (const float*)d_in[5];
    const float* b1   = (const float*)d_in[6];
    const float* W2   = (const float*)d_in[7];
    const float* a2s  = (const float*)d_in[8];
    const float* a2d  = (const float*)d_in[9];
    const float* b2   = (const float*)d_in[10];
    const float* fc_w = (const float*)d_in[11];
    const float* fc_b = (const float*)d_in[12];
    float* out = (float*)d_out;

    char* p = (char*)d_ws;
    auto alloc = [&](size_t bytes) -> char* {
        char* r = p; p += (bytes + 255) & ~(size_t)255; return r;
    };
    int*   deg     = (int*)alloc((size_t)NN * 4);
    int*   fill    = (int*)alloc((size_t)NN * 4);
    float* pool    = (float*)alloc((size_t)NG * 64 * 4);
    float* cnt     = (float*)alloc((size_t)NG * 4);
    size_t zero_bytes = (size_t)(p - (char*)d_ws);
    int*   offs    = (int*)alloc((size_t)(NN + 1) * 4);
    int*   partials= (int*)alloc(64 * 4);
    int*   csr     = (int*)alloc((size_t)EP * 4);
    float* asrc    = (float*)alloc((size_t)NN * 4 * 4);
    float* adst    = (float*)alloc((size_t)NN * 4 * 4);
    float* h       = (float*)alloc((size_t)NN * HC * 4);      // GEMM out (both layers)
    ushort_t* xhi  = (ushort_t*)alloc((size_t)MPAD * F_IN * 2);
    ushort_t* xlo  = (ushort_t*)alloc((size_t)MPAD * F_IN * 2);
    ushort_t* acthi= (ushort_t*)alloc((size_t)MPAD * HC * 2);
    ushort_t* actlo= (ushort_t*)alloc((size_t)MPAD * HC * 2);
    ushort_t* w1thi= (ushort_t*)alloc((size_t)HC * F_IN * 2); // [256][128]
    ushort_t* w1tlo= (ushort_t*)alloc((size_t)HC * F_IN * 2);
    ushort_t* w2thi= (ushort_t*)alloc((size_t)HC * HC * 2);   // [256][256]
    ushort_t* w2tlo= (ushort_t*)alloc((size_t)HC * HC * 2);
    float* out2    = (float*)acthi;  // alias: act planes dead after gemm2

    hipMemsetAsync(d_ws, 0, zero_bytes, stream);

    int eb = (EP + 255) / 256;
    edge_hist<<<eb, 256, 0, stream>>>(ei + NE, deg);
    scan_p1<<<49, 256, 0, stream>>>(deg, partials);
    scan_p3<<<49, 256, 0, stream>>>(deg, partials, offs);
    edge_fill<<<eb, 256, 0, stream>>>(ei, ei + NE, offs, fill, csr);

    // fp32 -> bf16 hi/lo splits
    int xn4 = NN * F_IN / 4;
    split_f32<<<(xn4 + 255) / 256, 256, 0, stream>>>(x, xhi, xlo, xn4);
    split_wT<<<(F_IN * HC + 255) / 256, 256, 0, stream>>>(W1, w1thi, w1tlo, F_IN, HC);
    split_wT<<<(HC * HC + 255) / 256, 256, 0, stream>>>(W2, w2thi, w2tlo, HC, HC);

    dim3 gg((NN + 127) / 128, HC / 128);
    int nb4 = (NN + 3) / 4;

    // layer 1
    gemm_bf3<<<gg, 256, 0, stream>>>(xhi, xlo, w1thi, w1tlo, h, NN, F_IN, HC);
    gat_alpha<<<nb4, 256, 0, stream>>>(h, a1s, a1d, asrc, adst);
    gat_agg<1><<<nb4, 256, 0, stream>>>(h, asrc, adst, offs, csr, b1, acthi, actlo, nullptr);
    // layer 2
    gemm_bf3<<<gg, 256, 0, stream>>>(acthi, actlo, w2thi, w2tlo, h, NN, HC, HC);
    gat_alpha<<<nb4, 256, 0, stream>>>(h, a2s, a2d, asrc, adst);
    gat_agg<0><<<nb4, 256, 0, stream>>>(h, asrc, adst, offs, csr, b2, nullptr, nullptr, out2);
    // readout
    pool_kernel<<<((NN + 15) / 16 + 3) / 4, 256, 0, stream>>>(out2, batch, pool, cnt);
    fc_kernel<<<(NG * NOUT + 255) / 256, 256, 0, stream>>>(pool, cnt, fc_w, fc_b, out);
}

// Round 3
// 443.882 us; speedup vs baseline: 1.4715x; 1.2695x over previous
//
#include <hip/hip_runtime.h>
#include <hip/hip_bf16.h>
#include <cstddef>
#include <cstdint>

// Problem constants (from reference)
#define NN 50000
#define MPAD 50048      // 391 tiles * 128
#define F_IN 128
#define NH 4
#define NC 64
#define NE 800000
#define NG 128
#define NOUT 8
#define HC 256          // NH*NC
#define EP (NE + NN)    // edges + self loops

typedef unsigned short ushort_t;
typedef __attribute__((ext_vector_type(8))) short bf16x8;
typedef __attribute__((ext_vector_type(8))) unsigned short u16x8;
typedef __attribute__((ext_vector_type(4))) float f32x4;

// ---------------------------------------------------------------------------
// helpers
// ---------------------------------------------------------------------------
__device__ __forceinline__ float lrelu02(float x) { return x > 0.0f ? x : 0.2f * x; }
__device__ __forceinline__ float elu1(float x)    { return x > 0.0f ? x : expm1f(x); }

__device__ __forceinline__ ushort_t f2bf(float f) {
    uint32_t u = __float_as_uint(f);
    uint32_t r = u + 0x7fffu + ((u >> 16) & 1u);
    return (ushort_t)(r >> 16);
}
__device__ __forceinline__ float bf2f(ushort_t h) {
    return __uint_as_float(((uint32_t)h) << 16);
}

// async global -> LDS, 16B per lane; lds dest = wave-uniform base + lane*16
__device__ __forceinline__ void gld16(const void* g, void* l) {
    __builtin_amdgcn_global_load_lds(
        (const __attribute__((address_space(1))) unsigned int*)g,
        (__attribute__((address_space(3))) unsigned int*)l, 16, 0, 0);
}

// ---------------------------------------------------------------------------
// CSR build: degree histogram -> exclusive scan -> fill (src ids, dst-sorted)
// ---------------------------------------------------------------------------
__global__ void edge_hist(const int* __restrict__ edst, int* __restrict__ deg) {
    int e = blockIdx.x * blockDim.x + threadIdx.x;
    if (e >= EP) return;
    int d = (e < NE) ? edst[e] : (e - NE);
    atomicAdd(&deg[d], 1);
}

__global__ __launch_bounds__(256) void scan_p1(const int* __restrict__ deg,
                                               int* __restrict__ partials) {
    __shared__ int lds[256];
    int b = blockIdx.x, t = threadIdx.x;
    int i0 = b * 1024 + t * 4;
    int s = 0;
#pragma unroll
    for (int j = 0; j < 4; j++) { int i = i0 + j; if (i < NN) s += deg[i]; }
    lds[t] = s;
    __syncthreads();
    for (int o = 128; o; o >>= 1) { if (t < o) lds[t] += lds[t + o]; __syncthreads(); }
    if (t == 0) partials[b] = lds[0];
}

__global__ __launch_bounds__(256) void scan_p3(const int* __restrict__ deg,
                                               const int* __restrict__ partials,
                                               int* __restrict__ offs) {
    __shared__ int lds[256];
    __shared__ int base_s;
    int b = blockIdx.x, t = threadIdx.x;
    if (t == 0) {
        int s = 0;
        for (int i = 0; i < b; i++) s += partials[i];
        base_s = s;
        if (b == 0) offs[0] = 0;
    }
    int i0 = b * 1024 + t * 4;
    int v[4]; int s = 0;
#pragma unroll
    for (int j = 0; j < 4; j++) { int i = i0 + j; v[j] = (i < NN) ? deg[i] : 0; s += v[j]; }
    lds[t] = s;
    __syncthreads();
    for (int o = 1; o < 256; o <<= 1) {
        int x = (t >= o) ? lds[t - o] : 0;
        __syncthreads();
        lds[t] += x;
        __syncthreads();
    }
    int run = base_s + (lds[t] - s);
#pragma unroll
    for (int j = 0; j < 4; j++) { run += v[j]; int i = i0 + j; if (i < NN) offs[i + 1] = run; }
}

__global__ void edge_fill(const int* __restrict__ esrc, const int* __restrict__ edst,
                          const int* __restrict__ offs, int* __restrict__ fill,
                          int* __restrict__ csr) {
    int e = blockIdx.x * blockDim.x + threadIdx.x;
    if (e >= EP) return;
    int s, d;
    if (e < NE) { s = esrc[e]; d = edst[e]; } else { s = d = e - NE; }
    int pos = offs[d] + atomicAdd(&fill[d], 1);
    csr[pos] = s;
}

// ---------------------------------------------------------------------------
// fp32 -> (bf16 hi, bf16 lo) split, vectorized
// ---------------------------------------------------------------------------
__global__ void split_f32(const float* __restrict__ in, ushort_t* __restrict__ hi,
                          ushort_t* __restrict__ lo, int n4) {
    int i = blockIdx.x * blockDim.x + threadIdx.x;
    if (i >= n4) return;
    float4 v = ((const float4*)in)[i];
    ushort4 h, l;
    h.x = f2bf(v.x); l.x = f2bf(v.x - bf2f(h.x));
    h.y = f2bf(v.y); l.y = f2bf(v.y - bf2f(h.y));
    h.z = f2bf(v.z); l.z = f2bf(v.z - bf2f(h.z));
    h.w = f2bf(v.w); l.w = f2bf(v.w - bf2f(h.w));
    ((ushort4*)hi)[i] = h;
    ((ushort4*)lo)[i] = l;
}

// W [K,N] fp32 -> WT hi/lo [N,K] bf16 (transposed planes for MFMA B-operand)
__global__ void split_wT(const float* __restrict__ W, ushort_t* __restrict__ hiT,
                         ushort_t* __restrict__ loT, int K, int N) {
    int idx = blockIdx.x * blockDim.x + threadIdx.x;
    if (idx >= K * N) return;
    int k = idx / N, n = idx % N;
    float v = W[idx];
    ushort_t h = f2bf(v);
    hiT[n * K + k] = h;
    loT[n * K + k] = f2bf(v - bf2f(h));
}

// ---------------------------------------------------------------------------
// split-bf16 MFMA GEMM, fused GAT epilogue:
//   h = (Ahi+Alo)@(Bhi+Blo) (drop lo*lo), fp32 acc
//   writes: hbf[MPAD][256] bf16(h)  (coalesced via LDS repack)
//           asrc[n][4], adst[n][4]  (per-head attention dots; each wave's 64
//           output cols == exactly one head, so dot = in-reg + 16-lane shfl)
// Block: 256 thr (4 waves 2x2), tile 128x128, BK=32, mfma_f32_16x16x32_bf16.
// C/D: col=lane&15, row=quad*4+reg (m89/m91-verified).
// ---------------------------------------------------------------------------
__global__ __launch_bounds__(256, 2) void gemm_gat(
        const ushort_t* __restrict__ Ahi, const ushort_t* __restrict__ Alo,
        const ushort_t* __restrict__ BThi, const ushort_t* __restrict__ BTlo,
        const float* __restrict__ a_s, const float* __restrict__ a_d,
        ushort_t* __restrict__ hbf, float* __restrict__ asrc,
        float* __restrict__ adst, int M, int K) {
    __shared__ alignas(16) ushort_t lds_all[4 * 128 * 32];   // 32 KB
    ushort_t* lAhi = lds_all;
    ushort_t* lAlo = lds_all + 4096;
    ushort_t* lBhi = lds_all + 8192;
    ushort_t* lBlo = lds_all + 12288;

    int t = threadIdx.x;
    int wave = t >> 6, lane = t & 63;
    int wm = wave >> 1, wn = wave & 1;
    int quad = lane >> 4, l15 = lane & 15;
    int tileM = blockIdx.x * 128;
    int tileN = blockIdx.y * 128;

    f32x4 acc[4][4];
#pragma unroll
    for (int f = 0; f < 4; f++)
#pragma unroll
        for (int g = 0; g < 4; g++) acc[f][g] = (f32x4){0.f, 0.f, 0.f, 0.f};

    int c0 = wave * 2;
    for (int k0 = 0; k0 < K; k0 += 32) {
        __syncthreads();
#pragma unroll
        for (int i = 0; i < 2; i++) {
            int c = c0 + i;
            int row = c * 16 + (lane >> 2);
            int kk = k0 + (lane & 3) * 8;
            size_t aoff = (size_t)(tileM + row) * K + kk;
            size_t boff = (size_t)(tileN + row) * K + kk;
            gld16(Ahi + aoff, &lAhi[c * 512]);
            gld16(Alo + aoff, &lAlo[c * 512]);
            gld16(BThi + boff, &lBhi[c * 512]);
            gld16(BTlo + boff, &lBlo[c * 512]);
        }
        __syncthreads();

        bf16x8 ah[4], al[4], bh[4], bl[4];
#pragma unroll
        for (int f = 0; f < 4; f++) {
            int m = wm * 64 + f * 16 + l15;
            ah[f] = *(const bf16x8*)&lAhi[m * 32 + quad * 8];
            al[f] = *(const bf16x8*)&lAlo[m * 32 + quad * 8];
        }
#pragma unroll
        for (int g = 0; g < 4; g++) {
            int n = wn * 64 + g * 16 + l15;
            bh[g] = *(const bf16x8*)&lBhi[n * 32 + quad * 8];
            bl[g] = *(const bf16x8*)&lBlo[n * 32 + quad * 8];
        }
#pragma unroll
        for (int f = 0; f < 4; f++)
#pragma unroll
            for (int g = 0; g < 4; g++) {
                acc[f][g] = __builtin_amdgcn_mfma_f32_16x16x32_bf16(ah[f], bh[g], acc[f][g], 0, 0, 0);
                acc[f][g] = __builtin_amdgcn_mfma_f32_16x16x32_bf16(ah[f], bl[g], acc[f][g], 0, 0, 0);
                acc[f][g] = __builtin_amdgcn_mfma_f32_16x16x32_bf16(al[f], bh[g], acc[f][g], 0, 0, 0);
            }
    }

    // ---- epilogue 1: per-head attention dots (this wave's 64 cols = 1 head)
    int head = (blockIdx.y << 1) | wn;
    float as_v[4], ad_v[4];
#pragma unroll
    for (int g = 0; g < 4; g++) {
        as_v[g] = a_s[head * 64 + g * 16 + l15];
        ad_v[g] = a_d[head * 64 + g * 16 + l15];
    }
#pragma unroll
    for (int f = 0; f < 4; f++) {
#pragma unroll
        for (int r = 0; r < 4; r++) {
            float ps = acc[f][0][r] * as_v[0] + acc[f][1][r] * as_v[1]
                     + acc[f][2][r] * as_v[2] + acc[f][3][r] * as_v[3];
            float pd = acc[f][0][r] * ad_v[0] + acc[f][1][r] * ad_v[1]
                     + acc[f][2][r] * ad_v[2] + acc[f][3][r] * ad_v[3];
#pragma unroll
            for (int o = 1; o < 16; o <<= 1) {
                ps += __shfl_xor(ps, o);
                pd += __shfl_xor(pd, o);
            }
            int row = tileM + wm * 64 + f * 16 + quad * 4 + r;
            if (l15 == 0 && row < M) {
                asrc[row * 4 + head] = ps;
                adst[row * 4 + head] = pd;
            }
        }
    }

    // ---- epilogue 2: bf16 h tile via LDS repack, coalesced 16B/lane stores
    __syncthreads();   // K-loop staging LDS dead
    ushort_t* lC = lds_all;   // [128 rows][128 cols]
#pragma unroll
    for (int f = 0; f < 4; f++)
#pragma unroll
        for (int g = 0; g < 4; g++)
#pragma unroll
            for (int r = 0; r < 4; r++)
                lC[(wm * 64 + f * 16 + quad * 4 + r) * 128 + wn * 64 + g * 16 + l15] =
                    f2bf(acc[f][g][r]);
    __syncthreads();
#pragma unroll
    for (int it = 0; it < 8; it++) {
        int row = wave * 32 + it * 4 + (lane >> 4);
        u16x8 v = *(const u16x8*)&lC[row * 128 + l15 * 8];
        *(u16x8*)(hbf + (size_t)(tileM + row) * 256 + tileN + l15 * 8) = v;
    }
}

// ---------------------------------------------------------------------------
// GAT aggregation: one wave per destination node, lanes = 64 channels.
// Pass 1: online softmax over edges (logits 1/lane for deg<=64).
// Pass 2: bf16 gather of h[src] (512B/edge), unroll 4 -> 16 loads in flight.
// CONCAT=1: writes bf16 hi/lo split of elu(acc+b) (feeds gemm layer 2).
// CONCAT=0: writes fp32 mean over heads + bias.
// ---------------------------------------------------------------------------
template <int CONCAT>
__global__ __launch_bounds__(256) void gat_agg(const ushort_t* __restrict__ hbf,
                                               const float* __restrict__ asrc,
                                               const float* __restrict__ adst,
                                               const int* __restrict__ offs,
                                               const int* __restrict__ csr,
                                               const float* __restrict__ bias,
                                               ushort_t* __restrict__ oh,
                                               ushort_t* __restrict__ ol,
                                               float* __restrict__ of) {
    int wave = threadIdx.x >> 6, lane = threadIdx.x & 63;
    int node = blockIdx.x * 4 + wave;
    if (node >= NN) return;
    int start = offs[node];
    int deg = offs[node + 1] - start;
    float4 ad = *(const float4*)(adst + node * 4);

    float m0 = -1e30f, m1 = -1e30f, m2 = -1e30f, m3 = -1e30f;
    float s0 = 0.f, s1 = 0.f, s2 = 0.f, s3 = 0.f;
    float e0 = 0.f, e1 = 0.f, e2 = 0.f, e3 = 0.f;
    int msrc = 0;
    for (int j = lane; j < deg; j += 64) {
        int sidx = csr[start + j];
        float4 as = *(const float4*)(asrc + sidx * 4);
        float t0 = lrelu02(as.x + ad.x);
        float t1 = lrelu02(as.y + ad.y);
        float t2 = lrelu02(as.z + ad.z);
        float t3 = lrelu02(as.w + ad.w);
        if (j == lane) { e0 = t0; e1 = t1; e2 = t2; e3 = t3; msrc = sidx; }
        float nm;
        nm = fmaxf(m0, t0); s0 = s0 * __expf(m0 - nm) + __expf(t0 - nm); m0 = nm;
        nm = fmaxf(m1, t1); s1 = s1 * __expf(m1 - nm) + __expf(t1 - nm); m1 = nm;
        nm = fmaxf(m2, t2); s2 = s2 * __expf(m2 - nm) + __expf(t2 - nm); m2 = nm;
        nm = fmaxf(m3, t3); s3 = s3 * __expf(m3 - nm) + __expf(t3 - nm); m3 = nm;
    }
    for (int o = 32; o; o >>= 1) {
        float om, os, nm;
        om = __shfl_xor(m0, o); os = __shfl_xor(s0, o);
        nm = fmaxf(m0, om); s0 = s0 * __expf(m0 - nm) + os * __expf(om - nm); m0 = nm;
        om = __shfl_xor(m1, o); os = __shfl_xor(s1, o);
        nm = fmaxf(m1, om); s1 = s1 * __expf(m1 - nm) + os * __expf(om - nm); m1 = nm;
        om = __shfl_xor(m2, o); os = __shfl_xor(s2, o);
        nm = fmaxf(m2, om); s2 = s2 * __expf(m2 - nm) + os * __expf(om - nm); m2 = nm;
        om = __shfl_xor(m3, o); os = __shfl_xor(s3, o);
        nm = fmaxf(m3, om); s3 = s3 * __expf(m3 - nm) + os * __expf(om - nm); m3 = nm;
    }
    float inv0 = 1.0f / (s0 + 1e-16f);
    float inv1 = 1.0f / (s1 + 1e-16f);
    float inv2 = 1.0f / (s2 + 1e-16f);
    float inv3 = 1.0f / (s3 + 1e-16f);

    float w0 = __expf(e0 - m0) * inv0;
    float w1 = __expf(e1 - m1) * inv1;
    float w2 = __expf(e2 - m2) * inv2;
    float w3 = __expf(e3 - m3) * inv3;

    float a0 = 0.f, a1 = 0.f, a2 = 0.f, a3 = 0.f;
    const ushort_t* hb = hbf + lane;
    int jmax = deg < 64 ? deg : 64;
#pragma unroll 4
    for (int j = 0; j < jmax; j++) {
        int sidx = __shfl(msrc, j);
        float u0 = __shfl(w0, j);
        float u1 = __shfl(w1, j);
        float u2 = __shfl(w2, j);
        float u3 = __shfl(w3, j);
        const ushort_t* hp = hb + (size_t)sidx * HC;
        a0 += u0 * bf2f(hp[0]);
        a1 += u1 * bf2f(hp[64]);
        a2 += u2 * bf2f(hp[128]);
        a3 += u3 * bf2f(hp[192]);
    }
    for (int j = 64; j < deg; j++) {  // correctness fallback (deg>64); not hit here
        int sidx = csr[start + j];
        float4 as = *(const float4*)(asrc + sidx * 4);
        float u0 = __expf(lrelu02(as.x + ad.x) - m0) * inv0;
        float u1 = __expf(lrelu02(as.y + ad.y) - m1) * inv1;
        float u2 = __expf(lrelu02(as.z + ad.z) - m2) * inv2;
        float u3 = __expf(lrelu02(as.w + ad.w) - m3) * inv3;
        const ushort_t* hp = hb + (size_t)sidx * HC;
        a0 += u0 * bf2f(hp[0]);
        a1 += u1 * bf2f(hp[64]);
        a2 += u2 * bf2f(hp[128]);
        a3 += u3 * bf2f(hp[192]);
    }

    if (CONCAT) {
        size_t base = (size_t)node * HC;
        float v0 = elu1(a0 + bias[lane]);
        float v1 = elu1(a1 + bias[64 + lane]);
        float v2 = elu1(a2 + bias[128 + lane]);
        float v3 = elu1(a3 + bias[192 + lane]);
        ushort_t h0 = f2bf(v0), h1 = f2bf(v1), h2 = f2bf(v2), h3 = f2bf(v3);
        oh[base + lane]       = h0; ol[base + lane]       = f2bf(v0 - bf2f(h0));
        oh[base + 64 + lane]  = h1; ol[base + 64 + lane]  = f2bf(v1 - bf2f(h1));
        oh[base + 128 + lane] = h2; ol[base + 128 + lane] = f2bf(v2 - bf2f(h2));
        oh[base + 192 + lane] = h3; ol[base + 192 + lane] = f2bf(v3 - bf2f(h3));
    } else {
        of[(size_t)node * NC + lane] = 0.25f * (a0 + a1 + a2 + a3) + bias[lane];
    }
}

// ---------------------------------------------------------------------------
// global mean pool (batch sorted) + FC
// ---------------------------------------------------------------------------
__global__ __launch_bounds__(256) void pool_kernel(const float* __restrict__ out2,
                                                   const int* __restrict__ batch,
                                                   float* __restrict__ pool,
                                                   float* __restrict__ cnt) {
    int gw = (blockIdx.x * blockDim.x + threadIdx.x) >> 6;
    int lane = threadIdx.x & 63;
    int start = gw * 16;
    if (start >= NN) return;
    int end = start + 16 < NN ? start + 16 : NN;
    int curg = batch[start];
    float acc = 0.f; int run = 0;
    for (int node = start; node < end; node++) {
        int g = batch[node];
        if (g != curg) {
            atomicAdd(&pool[curg * 64 + lane], acc);
            if (lane == 0) atomicAdd(&cnt[curg], (float)run);
            curg = g; acc = 0.f; run = 0;
        }
        acc += out2[(size_t)node * NC + lane];
        run++;
    }
    atomicAdd(&pool[curg * 64 + lane], acc);
    if (lane == 0) atomicAdd(&cnt[curg], (float)run);
}

__global__ void fc_kernel(const float* __restrict__ pool, const float* __restrict__ cnt,
                          const float* __restrict__ fc_w, const float* __restrict__ fc_b,
                          float* __restrict__ out) {
    int idx = blockIdx.x * blockDim.x + threadIdx.x;
    if (idx >= NG * NOUT) return;
    int g = idx >> 3, o = idx & 7;
    float inv = 1.0f / fmaxf(cnt[g], 1.0f);
    float s = 0.f;
#pragma unroll
    for (int c = 0; c < 64; c++) s += pool[g * 64 + c] * fc_w[c * 8 + o];
    out[idx] = s * inv + fc_b[o];
}

// ---------------------------------------------------------------------------
extern "C" void kernel_launch(void* const* d_in, const int* in_sizes, int n_in,
                              void* d_out, int out_size, void* d_ws, size_t ws_size,
                              hipStream_t stream) {
    const float* x    = (const float*)d_in[0];
    const int*   ei   = (const int*)d_in[1];   // [2, E]
    const int*   batch= (const int*)d_in[2];
    const float* W1   = (const float*)d_in[3];
    const float* a1s  = (const float*)d_in[4];
    const float* a1d  = (const float*)d_in[5];
    const float* b1   = (const float*)d_in[6];
    const float* W2   = (const float*)d_in[7];
    const float* a2s  = (const float*)d_in[8];
    const float* a2d  = (const float*)d_in[9];
    const float* b2   = (const float*)d_in[10];
    const float* fc_w = (const float*)d_in[11];
    const float* fc_b = (const float*)d_in[12];
    float* out = (float*)d_out;

    char* p = (char*)d_ws;
    auto alloc = [&](size_t bytes) -> char* {
        char* r = p; p += (bytes + 255) & ~(size_t)255; return r;
    };
    int*   deg     = (int*)alloc((size_t)NN * 4);
    int*   fill    = (int*)alloc((size_t)NN * 4);
    float* pool    = (float*)alloc((size_t)NG * 64 * 4);
    float* cnt     = (float*)alloc((size_t)NG * 4);
    size_t zero_bytes = (size_t)(p - (char*)d_ws);
    int*   offs    = (int*)alloc((size_t)(NN + 1) * 4);
    int*   partials= (int*)alloc(64 * 4);
    int*   csr     = (int*)alloc((size_t)EP * 4);
    float* asrc    = (float*)alloc((size_t)NN * 4 * 4);
    float* adst    = (float*)alloc((size_t)NN * 4 * 4);
    ushort_t* hbf  = (ushort_t*)alloc((size_t)MPAD * HC * 2); // bf16 h (both layers)
    ushort_t* xhi  = (ushort_t*)alloc((size_t)MPAD * F_IN * 2);
    ushort_t* xlo  = (ushort_t*)alloc((size_t)MPAD * F_IN * 2);
    ushort_t* acthi= (ushort_t*)alloc((size_t)MPAD * HC * 2);
    ushort_t* actlo= (ushort_t*)alloc((size_t)MPAD * HC * 2);
    ushort_t* w1thi= (ushort_t*)alloc((size_t)HC * F_IN * 2); // [256][128]
    ushort_t* w1tlo= (ushort_t*)alloc((size_t)HC * F_IN * 2);
    ushort_t* w2thi= (ushort_t*)alloc((size_t)HC * HC * 2);   // [256][256]
    ushort_t* w2tlo= (ushort_t*)alloc((size_t)HC * HC * 2);
    float* out2    = (float*)acthi;  // alias: act planes dead after gemm2

    hipMemsetAsync(d_ws, 0, zero_bytes, stream);

    int eb = (EP + 255) / 256;
    edge_hist<<<eb, 256, 0, stream>>>(ei + NE, deg);
    scan_p1<<<49, 256, 0, stream>>>(deg, partials);
    scan_p3<<<49, 256, 0, stream>>>(deg, partials, offs);
    edge_fill<<<eb, 256, 0, stream>>>(ei, ei + NE, offs, fill, csr);

    // fp32 -> bf16 hi/lo splits
    int xn4 = NN * F_IN / 4;
    split_f32<<<(xn4 + 255) / 256, 256, 0, stream>>>(x, xhi, xlo, xn4);
    split_wT<<<(F_IN * HC + 255) / 256, 256, 0, stream>>>(W1, w1thi, w1tlo, F_IN, HC);
    split_wT<<<(HC * HC + 255) / 256, 256, 0, stream>>>(W2, w2thi, w2tlo, HC, HC);

    dim3 gg((NN + 127) / 128, HC / 128);
    int nb4 = (NN + 3) / 4;

    // layer 1 (GEMM + fused alpha/bf16-h epilogue)
    gemm_gat<<<gg, 256, 0, stream>>>(xhi, xlo, w1thi, w1tlo, a1s, a1d,
                                     hbf, asrc, adst, NN, F_IN);
    gat_agg<1><<<nb4, 256, 0, stream>>>(hbf, asrc, adst, offs, csr, b1,
                                        acthi, actlo, nullptr);
    // layer 2
    gemm_gat<<<gg, 256, 0, stream>>>(acthi, actlo, w2thi, w2tlo, a2s, a2d,
                                     hbf, asrc, adst, NN, HC);
    gat_agg<0><<<nb4, 256, 0, stream>>>(hbf, asrc, adst, offs, csr, b2,
                                        nullptr, nullptr, out2);
    // readout
    pool_kernel<<<((NN + 15) / 16 + 3) / 4, 256, 0, stream>>>(out2, batch, pool, cnt);
    fc_kernel<<<(NG * NOUT + 255) / 256, 256, 0, stream>>>(pool, cnt, fc_w, fc_b, out);
}